// Round 1
// baseline (7012.154 us; speedup 1.0000x reference)
//
#include <hip/hip_runtime.h>
#include <hip/hip_bf16.h>

// Sizes (fixed by the reference)
#define B_ 32
#define S_ 128
#define H_ 1024
#define V_ 32000

using short8 = __attribute__((ext_vector_type(8))) short;
using f32x4  = __attribute__((ext_vector_type(4))) float;

__device__ inline unsigned short f2bf(float f) {
  unsigned u = __float_as_uint(f);
  unsigned r = u + 0x7FFFu + ((u >> 16) & 1u);  // RNE
  return (unsigned short)(r >> 16);
}

// ---------------- embedding gather -> bf16 [4096][1024] ----------------
__global__ void k_gather_embed(const int* __restrict__ idx, const float* __restrict__ E,
                               unsigned short* __restrict__ emb) {
  int g = blockIdx.x * blockDim.x + threadIdx.x;  // over 4096*128 (8 elems each)
  int n = g >> 7;
  int kv = (g & 127) * 8;
  const float4* src = reinterpret_cast<const float4*>(E + (size_t)idx[n] * H_ + kv);
  float4 a = src[0], b = src[1];
  unsigned short o[8] = {f2bf(a.x), f2bf(a.y), f2bf(a.z), f2bf(a.w),
                         f2bf(b.x), f2bf(b.y), f2bf(b.z), f2bf(b.w)};
  *reinterpret_cast<uint4*>(emb + (size_t)n * H_ + kv) = *reinterpret_cast<const uint4*>(o);
}

// ------------- concat + convert Wx{r,z,g} -> bf16 [1024][3072] -------------
__global__ void k_cvt_wxcat(const float* __restrict__ Wxr, const float* __restrict__ Wxz,
                            const float* __restrict__ Wxg, unsigned short* __restrict__ Wxcat) {
  int g = blockIdx.x * blockDim.x + threadIdx.x;  // over 1024*384 (8 elems each)
  int k = g / 384;
  int c8 = (g % 384) * 8;
  int m = c8 >> 10, j = c8 & 1023;
  const float* src = (m == 0 ? Wxr : (m == 1 ? Wxz : Wxg)) + (size_t)k * H_ + j;
  const float4* s4 = reinterpret_cast<const float4*>(src);
  float4 a = s4[0], b = s4[1];
  unsigned short o[8] = {f2bf(a.x), f2bf(a.y), f2bf(a.z), f2bf(a.w),
                         f2bf(b.x), f2bf(b.y), f2bf(b.z), f2bf(b.w)};
  *reinterpret_cast<uint4*>(Wxcat + (size_t)k * 3072 + c8) = *reinterpret_cast<const uint4*>(o);
}

// ---------------- convert Wout -> bf16 [1024][32000] ----------------
__global__ void k_cvt_wout(const float* __restrict__ W, unsigned short* __restrict__ Wb) {
  size_t g = (size_t)blockIdx.x * blockDim.x + threadIdx.x;  // over 32768000/8
  size_t off = g * 8;
  const float4* s4 = reinterpret_cast<const float4*>(W + off);
  float4 a = s4[0], b = s4[1];
  unsigned short o[8] = {f2bf(a.x), f2bf(a.y), f2bf(a.z), f2bf(a.w),
                         f2bf(b.x), f2bf(b.y), f2bf(b.z), f2bf(b.w)};
  *reinterpret_cast<uint4*>(Wb + off) = *reinterpret_cast<const uint4*>(o);
}

__global__ void k_bcat(const float* __restrict__ bxr, const float* __restrict__ bxz,
                       const float* __restrict__ bxg, float* __restrict__ bcat) {
  int j = blockIdx.x * blockDim.x + threadIdx.x;  // 3072
  bcat[j] = j < 1024 ? bxr[j] : (j < 2048 ? bxz[j - 1024] : bxg[j - 2048]);
}

// ---------------- bf16 MFMA GEMM: C[M][N] = A[M][K] * B[K][N] + bias[N] ----------------
// 128x128 tile, BK=32, 4 waves (2x2), each wave 64x64 via 4x4 frags of 16x16x32.
__launch_bounds__(256)
__global__ void k_gemm_bf16(const unsigned short* __restrict__ A, const unsigned short* __restrict__ Bm,
                            const float* __restrict__ bias, float* __restrict__ C,
                            int M, int N, int K) {
  __shared__ __align__(16) unsigned short la[128][40];  // [m][k], padded (+8) for banks
  __shared__ __align__(16) unsigned short lb[128][40];  // [n][k] (transposed), padded
  int tid = threadIdx.x;
  int m0 = blockIdx.y * 128, n0 = blockIdx.x * 128;
  int w = tid >> 6, lane = tid & 63;
  int wm = (w >> 1) * 64, wn = (w & 1) * 64;
  f32x4 acc[4][4] = {};

  for (int k0 = 0; k0 < K; k0 += 32) {
    __syncthreads();
    // stage A: 128x32 bf16, 16B vector loads
#pragma unroll
    for (int r = 0; r < 2; ++r) {
      int lin = r * 256 + tid;
      int m = lin >> 2, kv = (lin & 3) * 8;
      uint4 v = *reinterpret_cast<const uint4*>(A + (size_t)(m0 + m) * K + k0 + kv);
      *reinterpret_cast<uint4*>(&la[m][kv]) = v;
    }
    // stage B transposed: lb[n][k] = B[k0+k][n0+n]
#pragma unroll
    for (int r = 0; r < 16; ++r) {
      int lin = r * 256 + tid;
      int k = lin >> 7, n = lin & 127;
      lb[n][k] = Bm[(size_t)(k0 + k) * N + n0 + n];
    }
    __syncthreads();

    short8 af[4], bfr[4];
#pragma unroll
    for (int i = 0; i < 4; ++i)
      af[i] = *reinterpret_cast<const short8*>(&la[wm + i * 16 + (lane & 15)][(lane >> 4) * 8]);
#pragma unroll
    for (int i = 0; i < 4; ++i)
      bfr[i] = *reinterpret_cast<const short8*>(&lb[wn + i * 16 + (lane & 15)][(lane >> 4) * 8]);
#pragma unroll
    for (int mi = 0; mi < 4; ++mi)
#pragma unroll
      for (int ni = 0; ni < 4; ++ni)
        acc[mi][ni] = __builtin_amdgcn_mfma_f32_16x16x32_bf16(af[mi], bfr[ni], acc[mi][ni], 0, 0, 0);
  }

  // epilogue: C/D mapping col=lane&15, row=(lane>>4)*4+reg
#pragma unroll
  for (int mi = 0; mi < 4; ++mi) {
#pragma unroll
    for (int ni = 0; ni < 4; ++ni) {
      int col = n0 + wn + ni * 16 + (lane & 15);
      float bv = bias ? bias[col] : 0.f;
#pragma unroll
      for (int r = 0; r < 4; ++r) {
        int row = m0 + wm + mi * 16 + (lane >> 4) * 4 + r;
        C[(size_t)row * N + col] = acc[mi][ni][r] + bv;
      }
    }
  }
}

// ---------------- one GRU step (fp32, exact) ----------------
// grid 128 blocks: jt = blockIdx&3 (column tile of 256), b = blockIdx>>2.
// XCD = blockIdx%8 -> fixed jt per XCD -> weight slice (3MB) stays in that XCD's L2.
__launch_bounds__(256)
__global__ void k_gru_step(const float* __restrict__ xcat, const float* __restrict__ Whr,
                           const float* __restrict__ Whz, const float* __restrict__ Whg,
                           const float* __restrict__ bhr, const float* __restrict__ bhz,
                           const float* __restrict__ bhg, const float* __restrict__ hprev,
                           float* __restrict__ hnext, unsigned short* __restrict__ hidd, int s) {
  __shared__ float hs[H_];
  int tid = threadIdx.x;
  int jt = blockIdx.x & 3, b = blockIdx.x >> 2;
  reinterpret_cast<float4*>(hs)[tid] = reinterpret_cast<const float4*>(hprev + (size_t)b * H_)[tid];
  __syncthreads();
  int j = jt * 256 + tid;
  float ar = 0.f, az = 0.f, ag = 0.f;
#pragma unroll 4
  for (int k = 0; k < H_; ++k) {
    float hk = hs[k];
    ar = fmaf(hk, Whr[(size_t)k * H_ + j], ar);
    az = fmaf(hk, Whz[(size_t)k * H_ + j], az);
    ag = fmaf(hk, Whg[(size_t)k * H_ + j], ag);
  }
  size_t n = (size_t)b * S_ + s;
  const float* xrow = xcat + n * 3072;
  float xr = xrow[j], xz = xrow[1024 + j], xg = xrow[2048 + j];
  float r = 1.f / (1.f + __expf(-(xr + ar + bhr[j])));
  float z = 1.f / (1.f + __expf(-(xz + az + bhz[j])));
  float g = tanhf(xg + r * (ag + bhg[j]));
  float hn = (1.f - z) * g + z * hs[j];
  hnext[(size_t)b * H_ + j] = hn;
  hidd[n * H_ + j] = f2bf(hn);
}

extern "C" void kernel_launch(void* const* d_in, const int* in_sizes, int n_in,
                              void* d_out, int out_size, void* d_ws, size_t ws_size,
                              hipStream_t stream) {
  const int*   inputs      = (const int*)d_in[0];
  // d_in[1] = annotations: unused by reference
  const float* hidden_init = (const float*)d_in[2];
  const float* E    = (const float*)d_in[3];
  const float* Wxr  = (const float*)d_in[4];  const float* bxr = (const float*)d_in[5];
  const float* Wxz  = (const float*)d_in[6];  const float* bxz = (const float*)d_in[7];
  const float* Wxg  = (const float*)d_in[8];  const float* bxg = (const float*)d_in[9];
  const float* Whr  = (const float*)d_in[10]; const float* bhr = (const float*)d_in[11];
  const float* Whz  = (const float*)d_in[12]; const float* bhz = (const float*)d_in[13];
  const float* Whg  = (const float*)d_in[14]; const float* bhg = (const float*)d_in[15];
  const float* Wout = (const float*)d_in[16]; const float* bout = (const float*)d_in[17];
  float* out = (float*)d_out;

  // workspace layout (bytes)
  char* ws = (char*)d_ws;
  unsigned short* emb   = (unsigned short*)(ws);              //  8,388,608  emb bf16 [4096][1024]
  unsigned short* wxcat = (unsigned short*)(ws + 8388608);    //  6,291,456  Wx cat bf16 [1024][3072]
  unsigned short* woutb = (unsigned short*)(ws + 14680064);   // 65,536,000  Wout bf16 [1024][32000]
  float* bcat           = (float*)(ws + 80216064);            //     12,288  bias cat [3072]
  float* xcat           = (float*)(ws + 80228352);            // 50,331,648  x-projections fp32 [4096][3072]
  unsigned short* hidd  = (unsigned short*)(ws + 130560000);  //  8,388,608  hiddens bf16 [4096][1024]
  float* hbuf           = (float*)(ws + 138948608);           //    262,144  h ping-pong [2][32][1024]

  k_gather_embed<<<2048, 256, 0, stream>>>(inputs, E, emb);
  k_cvt_wxcat<<<1536, 256, 0, stream>>>(Wxr, Wxz, Wxg, wxcat);
  k_cvt_wout<<<16000, 256, 0, stream>>>(Wout, woutb);
  k_bcat<<<12, 256, 0, stream>>>(bxr, bxz, bxg, bcat);

  // x-projections: [4096][3072] = emb @ Wxcat + bcat
  dim3 gp(24, 32);
  k_gemm_bf16<<<gp, 256, 0, stream>>>(emb, wxcat, bcat, xcat, 4096, 3072, 1024);

  // sequential recurrence, fp32
  float* h0 = hbuf;
  float* h1 = hbuf + B_ * H_;
  for (int s = 0; s < S_; ++s) {
    const float* hp = (s == 0) ? hidden_init : ((s & 1) ? h0 : h1);
    float* hx = (s & 1) ? h1 : h0;
    k_gru_step<<<128, 256, 0, stream>>>(xcat, Whr, Whz, Whg, bhr, bhz, bhg, hp, hx, hidd, s);
  }

  // output: [4096][32000] = hiddens @ Wout + bout
  dim3 go(250, 32);
  k_gemm_bf16<<<go, 256, 0, stream>>>(hidd, woutb, bout, out, 4096, 32000, 1024);
}

// Round 2
// 3864.693 us; speedup vs baseline: 1.8144x; 1.8144x over previous
//
#include <hip/hip_runtime.h>
#include <hip/hip_bf16.h>

#define B_ 32
#define S_ 128
#define H_ 1024
#define V_ 32000

using short8 = __attribute__((ext_vector_type(8))) short;
using f32x4  = __attribute__((ext_vector_type(4))) float;
typedef unsigned short u16;

__device__ inline u16 f2bf(float f) {
  unsigned u = __float_as_uint(f);
  unsigned r = u + 0x7FFFu + ((u >> 16) & 1u);  // RNE
  return (u16)(r >> 16);
}
__device__ inline float bf2f(u16 h) { return __uint_as_float(((unsigned)h) << 16); }

__device__ inline void gload_lds16(const void* g, void* l) {
  __builtin_amdgcn_global_load_lds((const __attribute__((address_space(1))) unsigned int*)g,
                                   (__attribute__((address_space(3))) unsigned int*)l, 16, 0, 0);
}

// ---- A-frag layout: unit(kt, mt, l) = (kt*MT + mt)*64 + l ; 8 bf16 per unit ----
// element: row = mt*16 + (l&15), k = kt*32 + (l>>4)*8 + j
// ---- B-frag layout: unit(kt, nf, l) = (kt*NT + nf)*64 + l ----
// element: col = nf*16 + (l&15), k = kt*32 + (l>>4)*8 + j

// embedding gather -> A-frag order bf16 (M=4096, K=1024)
__global__ void k_gather_embed(const int* __restrict__ idx, const float* __restrict__ E,
                               u16* __restrict__ embf) {
  int g = blockIdx.x * blockDim.x + threadIdx.x;      // 524288 units
  int kt = g >> 14, rem = g & 16383, mt = rem >> 6, l = rem & 63;
  int row = mt * 16 + (l & 15);
  int k = kt * 32 + ((l >> 4) << 3);
  const float4* src = reinterpret_cast<const float4*>(E + (size_t)idx[row] * H_ + k);
  float4 a = src[0], b = src[1];
  u16 o[8] = {f2bf(a.x), f2bf(a.y), f2bf(a.z), f2bf(a.w),
              f2bf(b.x), f2bf(b.y), f2bf(b.z), f2bf(b.w)};
  *reinterpret_cast<uint4*>(embf + (size_t)g * 8) = *reinterpret_cast<const uint4*>(o);
}

// Wx{r,z,g} -> B-frag order (K=1024, N=3072 concat)
__global__ void k_cvt_wx(const float* __restrict__ Wxr, const float* __restrict__ Wxz,
                         const float* __restrict__ Wxg, u16* __restrict__ wxf) {
  int g = blockIdx.x * blockDim.x + threadIdx.x;      // 393216 units (kt*192+nf)*64+l
  int kt = g / 12288, rem = g % 12288, nf = rem >> 6, l = rem & 63;
  int col = nf * 16 + (l & 15);
  int gate = col >> 10, j = col & 1023;
  int k0 = kt * 32 + ((l >> 4) << 3);
  const float* W = gate == 0 ? Wxr : (gate == 1 ? Wxz : Wxg);
  u16 o[8];
#pragma unroll
  for (int e = 0; e < 8; ++e) o[e] = f2bf(W[(size_t)(k0 + e) * H_ + j]);
  *reinterpret_cast<uint4*>(wxf + (size_t)g * 8) = *reinterpret_cast<const uint4*>(o);
}

// Wout -> B-frag order (K=1024, N=32000)
__global__ void k_cvt_wout(const float* __restrict__ W, u16* __restrict__ wof) {
  int g = blockIdx.x * blockDim.x + threadIdx.x;      // 4096000 units (kt*2000+nf)*64+l
  int kt = g / 128000, rem = g - kt * 128000, nf = rem >> 6, l = rem & 63;
  int col = nf * 16 + (l & 15);
  int k0 = kt * 32 + ((l >> 4) << 3);
  u16 o[8];
#pragma unroll
  for (int e = 0; e < 8; ++e) o[e] = f2bf(W[(size_t)(k0 + e) * V_ + col]);
  *reinterpret_cast<uint4*>(wof + (size_t)g * 8) = *reinterpret_cast<const uint4*>(o);
}

// Wh{r,z,g} -> hi/lo split, recurrence frag order: unit(nf, kt, l) = (nf*32 + kt)*64 + l
// nf = gate*64 + w ; col = (nf&63)*16 + (l&15), k = kt*32 + (l>>4)*8 + j
__global__ void k_prep_wh(const float* __restrict__ Whr, const float* __restrict__ Whz,
                          const float* __restrict__ Whg, u16* __restrict__ whh,
                          u16* __restrict__ whl) {
  int g = blockIdx.x * blockDim.x + threadIdx.x;      // 393216 units
  int nf = g >> 11, rem = g & 2047, kt = rem >> 6, l = rem & 63;
  int gate = nf >> 6;
  int col = (nf & 63) * 16 + (l & 15);
  int k0 = kt * 32 + ((l >> 4) << 3);
  const float* W = gate == 0 ? Whr : (gate == 1 ? Whz : Whg);
  u16 oh[8], ol[8];
#pragma unroll
  for (int e = 0; e < 8; ++e) {
    float v = W[(size_t)(k0 + e) * H_ + col];
    u16 hi = f2bf(v);
    oh[e] = hi;
    ol[e] = f2bf(v - bf2f(hi));
  }
  *reinterpret_cast<uint4*>(whh + (size_t)g * 8) = *reinterpret_cast<const uint4*>(oh);
  *reinterpret_cast<uint4*>(whl + (size_t)g * 8) = *reinterpret_cast<const uint4*>(ol);
}

__global__ void k_prep_h0(const float* __restrict__ h0, float* __restrict__ hp,
                          u16* __restrict__ hh, u16* __restrict__ hl) {
  int i = blockIdx.x * blockDim.x + threadIdx.x;  // 32768
  float v = h0[i];
  hp[i] = v;
  u16 hi = f2bf(v);
  hh[i] = hi;
  hl[i] = f2bf(v - bf2f(hi));
}

__global__ void k_bcat(const float* __restrict__ bxr, const float* __restrict__ bxz,
                       const float* __restrict__ bxg, float* __restrict__ bcat) {
  int j = blockIdx.x * blockDim.x + threadIdx.x;  // 3072
  bcat[j] = j < 1024 ? bxr[j] : (j < 2048 ? bxz[j - 1024] : bxg[j - 2048]);
}

// ---------- m97-style GEMM on frag-order inputs: C[M][N] = A*B + bias ----------
__launch_bounds__(256, 2)
__global__ void k_gemm_frag(const u16* __restrict__ Af, const u16* __restrict__ Bf,
                            const float* __restrict__ bias, float* __restrict__ C,
                            int MT, int NT, int KT, int N) {
  __shared__ __align__(16) u16 lA[2 * 512 * 8];
  __shared__ __align__(16) u16 lB[2 * 512 * 8];
  int tid = threadIdx.x, w = tid >> 6, lane = tid & 63;
  int mt0 = blockIdx.y * 8, nf0 = blockIdx.x * 8;
  int wm = (w >> 1) * 4, wn = (w & 1) * 4;
  f32x4 acc[4][4] = {};
  for (int kt = 0; kt < KT; kt += 2) {
    __syncthreads();
#pragma unroll
    for (int hh = 0; hh < 2; ++hh) {
      const u16* ga = Af + ((size_t)(kt + hh) * MT + mt0) * 512;
      const u16* gb = Bf + ((size_t)(kt + hh) * NT + nf0) * 512;
#pragma unroll
      for (int r = 0; r < 2; ++r) {
        int ub = (r * 4 + w) * 64;
        gload_lds16(ga + (size_t)(ub + lane) * 8, lA + (size_t)(hh * 512 + ub) * 8);
        gload_lds16(gb + (size_t)(ub + lane) * 8, lB + (size_t)(hh * 512 + ub) * 8);
      }
    }
    __syncthreads();
#pragma unroll
    for (int hh = 0; hh < 2; ++hh) {
      short8 af[4], bfr[4];
#pragma unroll
      for (int i = 0; i < 4; ++i) {
        af[i]  = *reinterpret_cast<const short8*>(lA + ((hh * 8 + wm + i) * 64 + lane) * 8);
        bfr[i] = *reinterpret_cast<const short8*>(lB + ((hh * 8 + wn + i) * 64 + lane) * 8);
      }
#pragma unroll
      for (int mi = 0; mi < 4; ++mi)
#pragma unroll
        for (int ni = 0; ni < 4; ++ni)
          acc[mi][ni] = __builtin_amdgcn_mfma_f32_16x16x32_bf16(af[mi], bfr[ni], acc[mi][ni], 0, 0, 0);
    }
  }
  int m0 = mt0 * 16, n0 = nf0 * 16;
#pragma unroll
  for (int ni = 0; ni < 4; ++ni) {
    int col = n0 + (wn + ni) * 16 + (lane & 15);
    float bv = bias[col];
#pragma unroll
    for (int mi = 0; mi < 4; ++mi) {
#pragma unroll
      for (int q = 0; q < 4; ++q) {
        int row = m0 + (wm + mi) * 16 + ((lane >> 4) << 2) + q;
        C[(size_t)row * N + col] = acc[mi][ni][q] + bv;
      }
    }
  }
}

// ---------- GRU step: 64 blocks x 1 wave; wave w owns hidden cols [16w,16w+16) ----------
// fp32-exact via hi/lo split: h@W = h_hi@W_hi + h_hi@W_lo + h_lo@W_hi
__launch_bounds__(64)
__global__ void k_gru_step(const u16* __restrict__ whh, const u16* __restrict__ whl,
                           const float* __restrict__ xcat, const float* __restrict__ bhr,
                           const float* __restrict__ bhz, const float* __restrict__ bhg,
                           const float* __restrict__ hp, const u16* __restrict__ hph,
                           const u16* __restrict__ hpl, float* __restrict__ hn,
                           u16* __restrict__ hnh, u16* __restrict__ hnl,
                           u16* __restrict__ hiddf, int s) {
  int w = blockIdx.x, l = threadIdx.x;
  int lr = l & 15, lk = (l >> 4) << 3;
  f32x4 acc[3][2] = {};
#pragma unroll 4
  for (int kt = 0; kt < 32; ++kt) {
    int k = kt * 32 + lk;
    short8 ah0 = *reinterpret_cast<const short8*>(hph + (size_t)lr * H_ + k);
    short8 ah1 = *reinterpret_cast<const short8*>(hph + (size_t)(lr + 16) * H_ + k);
    short8 al0 = *reinterpret_cast<const short8*>(hpl + (size_t)lr * H_ + k);
    short8 al1 = *reinterpret_cast<const short8*>(hpl + (size_t)(lr + 16) * H_ + k);
#pragma unroll
    for (int g = 0; g < 3; ++g) {
      size_t u = (((size_t)(g * 64 + w) * 32 + kt) * 64 + l) * 8;
      short8 bh = *reinterpret_cast<const short8*>(whh + u);
      short8 bl = *reinterpret_cast<const short8*>(whl + u);
      acc[g][0] = __builtin_amdgcn_mfma_f32_16x16x32_bf16(ah0, bh, acc[g][0], 0, 0, 0);
      acc[g][1] = __builtin_amdgcn_mfma_f32_16x16x32_bf16(ah1, bh, acc[g][1], 0, 0, 0);
      acc[g][0] = __builtin_amdgcn_mfma_f32_16x16x32_bf16(ah0, bl, acc[g][0], 0, 0, 0);
      acc[g][1] = __builtin_amdgcn_mfma_f32_16x16x32_bf16(ah1, bl, acc[g][1], 0, 0, 0);
      acc[g][0] = __builtin_amdgcn_mfma_f32_16x16x32_bf16(al0, bh, acc[g][0], 0, 0, 0);
      acc[g][1] = __builtin_amdgcn_mfma_f32_16x16x32_bf16(al1, bh, acc[g][1], 0, 0, 0);
    }
  }
  int j = w * 16 + lr;
  float br = bhr[j], bz = bhz[j], bg = bhg[j];
#pragma unroll
  for (int mt = 0; mt < 2; ++mt) {
#pragma unroll
    for (int q = 0; q < 4; ++q) {
      int b = mt * 16 + ((l >> 4) << 2) + q;
      const float* xr = xcat + (size_t)(b * S_ + s) * 3072;
      float ar = acc[0][mt][q] + br + xr[j];
      float az = acc[1][mt][q] + bz + xr[1024 + j];
      float ag = acc[2][mt][q] + bg;
      float r = 1.f / (1.f + __expf(-ar));
      float z = 1.f / (1.f + __expf(-az));
      float ta = xr[2048 + j] + r * ag;
      float gv = 1.f - 2.f / (__expf(2.f * ta) + 1.f);  // tanh
      float hprev = hp[(size_t)b * H_ + j];
      float hnew = (1.f - z) * gv + z * hprev;
      hn[(size_t)b * H_ + j] = hnew;
      u16 hi = f2bf(hnew);
      hnh[(size_t)b * H_ + j] = hi;
      hnl[(size_t)b * H_ + j] = f2bf(hnew - bf2f(hi));
      // hidd in A-frag order for the output GEMM: row = b*128 + s, k = j
      int row = b * S_ + s;
      int ktO = j >> 5, mtO = row >> 4, laneO = (row & 15) + 16 * ((j >> 3) & 3);
      hiddf[(((size_t)ktO * 256 + mtO) * 64 + laneO) * 8 + (j & 7)] = hi;
    }
  }
}

extern "C" void kernel_launch(void* const* d_in, const int* in_sizes, int n_in,
                              void* d_out, int out_size, void* d_ws, size_t ws_size,
                              hipStream_t stream) {
  const int*   inputs      = (const int*)d_in[0];
  const float* hidden_init = (const float*)d_in[2];
  const float* E    = (const float*)d_in[3];
  const float* Wxr  = (const float*)d_in[4];  const float* bxr = (const float*)d_in[5];
  const float* Wxz  = (const float*)d_in[6];  const float* bxz = (const float*)d_in[7];
  const float* Wxg  = (const float*)d_in[8];  const float* bxg = (const float*)d_in[9];
  const float* Whr  = (const float*)d_in[10]; const float* bhr = (const float*)d_in[11];
  const float* Whz  = (const float*)d_in[12]; const float* bhz = (const float*)d_in[13];
  const float* Whg  = (const float*)d_in[14]; const float* bhg = (const float*)d_in[15];
  const float* Wout = (const float*)d_in[16]; const float* bout = (const float*)d_in[17];
  float* out = (float*)d_out;

  char* ws = (char*)d_ws;
  u16* wxf    = (u16*)(ws);                    //  6,291,456
  u16* wof    = (u16*)(ws + 6291456);          // 65,536,000
  u16* embf   = (u16*)(ws + 71827456);         //  8,388,608 (aliased: hiddf after xproj)
  u16* hiddf  = embf;                          //  alias — emb fully consumed by xproj first
  float* bcat = (float*)(ws + 80216064);       //     12,288
  float* xcat = (float*)(ws + 80228352);       // 50,331,648
  u16* whh    = (u16*)(ws + 130560000);        //  6,291,456
  u16* whl    = (u16*)(ws + 136851456);        //  6,291,456
  float* hpb  = (float*)(ws + 143142912);      //    262,144 (2 slots)
  u16* hhb    = (u16*)(ws + 143405056);        //    131,072 (2 slots)
  u16* hlb    = (u16*)(ws + 143536128);        //    131,072 (2 slots)

  k_gather_embed<<<2048, 256, 0, stream>>>(inputs, E, embf);
  k_cvt_wx<<<1536, 256, 0, stream>>>(Wxr, Wxz, Wxg, wxf);
  k_cvt_wout<<<16000, 256, 0, stream>>>(Wout, wof);
  k_prep_wh<<<1536, 256, 0, stream>>>(Whr, Whz, Whg, whh, whl);
  k_prep_h0<<<128, 256, 0, stream>>>(hidden_init, hpb, hhb, hlb);
  k_bcat<<<12, 256, 0, stream>>>(bxr, bxz, bxg, bcat);

  // x-projections: [4096][3072] fp32
  k_gemm_frag<<<dim3(24, 32), 256, 0, stream>>>(embf, wxf, bcat, xcat, 256, 192, 32, 3072);

  // recurrence
  for (int s = 0; s < S_; ++s) {
    int pi = s & 1, po = pi ^ 1;
    k_gru_step<<<64, 64, 0, stream>>>(whh, whl, xcat, bhr, bhz, bhg,
                                      hpb + pi * (B_ * H_), hhb + pi * (B_ * H_), hlb + pi * (B_ * H_),
                                      hpb + po * (B_ * H_), hhb + po * (B_ * H_), hlb + po * (B_ * H_),
                                      hiddf, s);
  }

  // output: [4096][32000] fp32
  k_gemm_frag<<<dim3(250, 32), 256, 0, stream>>>(hiddf, wof, bout, out, 256, 2000, 32, 32000);
}

// Round 3
// 1636.526 us; speedup vs baseline: 4.2848x; 2.3615x over previous
//
#include <hip/hip_runtime.h>
#include <hip/hip_bf16.h>

#define B_ 32
#define S_ 128
#define H_ 1024
#define V_ 32000

using short8 = __attribute__((ext_vector_type(8))) short;
using f32x4  = __attribute__((ext_vector_type(4))) float;
typedef unsigned short u16;

__device__ inline u16 f2bf(float f) {
  unsigned u = __float_as_uint(f);
  unsigned r = u + 0x7FFFu + ((u >> 16) & 1u);  // RNE
  return (u16)(r >> 16);
}
__device__ inline float bf2f(u16 h) { return __uint_as_float(((unsigned)h) << 16); }

__device__ inline void gload_lds16(const void* g, void* l) {
  __builtin_amdgcn_global_load_lds((const __attribute__((address_space(1))) unsigned int*)g,
                                   (__attribute__((address_space(3))) unsigned int*)l, 16, 0, 0);
}

// ---- A-frag layout: unit(kt, mt, l) = (kt*MT + mt)*64 + l ; 8 bf16 per unit ----
// element: row = mt*16 + (l&15), k = kt*32 + (l>>4)*8 + j
// ---- B-frag layout: unit(kt, nf, l) = (kt*NT + nf)*64 + l ----

// embedding gather -> A-frag order bf16 (M=4096, K=1024)
__global__ void k_gather_embed(const int* __restrict__ idx, const float* __restrict__ E,
                               u16* __restrict__ embf) {
  int g = blockIdx.x * blockDim.x + threadIdx.x;      // 524288 units
  int kt = g >> 14, rem = g & 16383, mt = rem >> 6, l = rem & 63;
  int row = mt * 16 + (l & 15);
  int k = kt * 32 + ((l >> 4) << 3);
  const float4* src = reinterpret_cast<const float4*>(E + (size_t)idx[row] * H_ + k);
  float4 a = src[0], b = src[1];
  u16 o[8] = {f2bf(a.x), f2bf(a.y), f2bf(a.z), f2bf(a.w),
              f2bf(b.x), f2bf(b.y), f2bf(b.z), f2bf(b.w)};
  *reinterpret_cast<uint4*>(embf + (size_t)g * 8) = *reinterpret_cast<const uint4*>(o);
}

// Wx{r,z,g} -> B-frag order (K=1024, N=3072 concat)
__global__ void k_cvt_wx(const float* __restrict__ Wxr, const float* __restrict__ Wxz,
                         const float* __restrict__ Wxg, u16* __restrict__ wxf) {
  int g = blockIdx.x * blockDim.x + threadIdx.x;      // 393216 units (kt*192+nf)*64+l
  int kt = g / 12288, rem = g % 12288, nf = rem >> 6, l = rem & 63;
  int col = nf * 16 + (l & 15);
  int gate = col >> 10, j = col & 1023;
  int k0 = kt * 32 + ((l >> 4) << 3);
  const float* W = gate == 0 ? Wxr : (gate == 1 ? Wxz : Wxg);
  u16 o[8];
#pragma unroll
  for (int e = 0; e < 8; ++e) o[e] = f2bf(W[(size_t)(k0 + e) * H_ + j]);
  *reinterpret_cast<uint4*>(wxf + (size_t)g * 8) = *reinterpret_cast<const uint4*>(o);
}

// Wout -> B-frag order (K=1024, N=32000)
__global__ void k_cvt_wout(const float* __restrict__ W, u16* __restrict__ wof) {
  int g = blockIdx.x * blockDim.x + threadIdx.x;      // 4096000 units (kt*2000+nf)*64+l
  int kt = g / 128000, rem = g - kt * 128000, nf = rem >> 6, l = rem & 63;
  int col = nf * 16 + (l & 15);
  int k0 = kt * 32 + ((l >> 4) << 3);
  u16 o[8];
#pragma unroll
  for (int e = 0; e < 8; ++e) o[e] = f2bf(W[(size_t)(k0 + e) * V_ + col]);
  *reinterpret_cast<uint4*>(wof + (size_t)g * 8) = *reinterpret_cast<const uint4*>(o);
}

// Wh{r,z,g} -> hi/lo split; recurrence layout: unit = ((jtile*3 + gate)*32 + kt)*64 + l
// col = jtile*16 + (l&15), k = kt*32 + (l>>4)*8 + j
__global__ void k_prep_wh(const float* __restrict__ Whr, const float* __restrict__ Whz,
                          const float* __restrict__ Whg, u16* __restrict__ whh,
                          u16* __restrict__ whl) {
  int g = blockIdx.x * blockDim.x + threadIdx.x;      // 393216 units
  int jtile = g / 6144, rem = g % 6144;
  int gate = rem >> 11, kt = (rem >> 6) & 31, l = rem & 63;
  int col = jtile * 16 + (l & 15);
  int k0 = kt * 32 + ((l >> 4) << 3);
  const float* W = gate == 0 ? Whr : (gate == 1 ? Whz : Whg);
  u16 oh[8], ol[8];
#pragma unroll
  for (int e = 0; e < 8; ++e) {
    float v = W[(size_t)(k0 + e) * H_ + col];
    u16 hi = f2bf(v);
    oh[e] = hi;
    ol[e] = f2bf(v - bf2f(hi));
  }
  *reinterpret_cast<uint4*>(whh + (size_t)g * 8) = *reinterpret_cast<const uint4*>(oh);
  *reinterpret_cast<uint4*>(whl + (size_t)g * 8) = *reinterpret_cast<const uint4*>(ol);
}

__global__ void k_prep_h0(const float* __restrict__ h0, float* __restrict__ hp,
                          u16* __restrict__ hh, u16* __restrict__ hl) {
  int i = blockIdx.x * blockDim.x + threadIdx.x;  // 32768
  float v = h0[i];
  hp[i] = v;
  u16 hi = f2bf(v);
  hh[i] = hi;
  hl[i] = f2bf(v - bf2f(hi));
}

__global__ void k_bcat(const float* __restrict__ bxr, const float* __restrict__ bxz,
                       const float* __restrict__ bxg, float* __restrict__ bcat) {
  int j = blockIdx.x * blockDim.x + threadIdx.x;  // 3072
  bcat[j] = j < 1024 ? bxr[j] : (j < 2048 ? bxz[j - 1024] : bxg[j - 2048]);
}

// ---------- m97-style GEMM on frag-order inputs: C[M][N] = A*B + bias ----------
__launch_bounds__(256, 2)
__global__ void k_gemm_frag(const u16* __restrict__ Af, const u16* __restrict__ Bf,
                            const float* __restrict__ bias, float* __restrict__ C,
                            int MT, int NT, int KT, int N) {
  __shared__ __align__(16) u16 lA[2 * 512 * 8];
  __shared__ __align__(16) u16 lB[2 * 512 * 8];
  int tid = threadIdx.x, w = tid >> 6, lane = tid & 63;
  int mt0 = blockIdx.y * 8, nf0 = blockIdx.x * 8;
  int wm = (w >> 1) * 4, wn = (w & 1) * 4;
  f32x4 acc[4][4] = {};
  for (int kt = 0; kt < KT; kt += 2) {
    __syncthreads();
#pragma unroll
    for (int hh = 0; hh < 2; ++hh) {
      const u16* ga = Af + ((size_t)(kt + hh) * MT + mt0) * 512;
      const u16* gb = Bf + ((size_t)(kt + hh) * NT + nf0) * 512;
#pragma unroll
      for (int r = 0; r < 2; ++r) {
        int ub = (r * 4 + w) * 64;
        gload_lds16(ga + (size_t)(ub + lane) * 8, lA + (size_t)(hh * 512 + ub) * 8);
        gload_lds16(gb + (size_t)(ub + lane) * 8, lB + (size_t)(hh * 512 + ub) * 8);
      }
    }
    __syncthreads();
#pragma unroll
    for (int hh = 0; hh < 2; ++hh) {
      short8 af[4], bfr[4];
#pragma unroll
      for (int i = 0; i < 4; ++i) {
        af[i]  = *reinterpret_cast<const short8*>(lA + ((hh * 8 + wm + i) * 64 + lane) * 8);
        bfr[i] = *reinterpret_cast<const short8*>(lB + ((hh * 8 + wn + i) * 64 + lane) * 8);
      }
#pragma unroll
      for (int mi = 0; mi < 4; ++mi)
#pragma unroll
        for (int ni = 0; ni < 4; ++ni)
          acc[mi][ni] = __builtin_amdgcn_mfma_f32_16x16x32_bf16(af[mi], bfr[ni], acc[mi][ni], 0, 0, 0);
    }
  }
  int m0 = mt0 * 16, n0 = nf0 * 16;
#pragma unroll
  for (int ni = 0; ni < 4; ++ni) {
    int col = n0 + (wn + ni) * 16 + (lane & 15);
    float bv = bias[col];
#pragma unroll
    for (int mi = 0; mi < 4; ++mi) {
#pragma unroll
      for (int q = 0; q < 4; ++q) {
        int row = m0 + (wm + mi) * 16 + ((lane >> 4) << 2) + q;
        C[(size_t)row * N + col] = acc[mi][ni][q] + bv;
      }
    }
  }
}

// ---------- GRU step: 128 blocks (mhalf*64 + jtile) x 12 waves ----------
// wave = (gate = w>>2, kgroup = w&3): K-slice of 256, one 16x16 acc.
// fp32-exact via hi/lo split: h@W = h_hi@W_hi + h_hi@W_lo + h_lo@W_hi
__launch_bounds__(768, 1)
__global__ void k_gru_step(const u16* __restrict__ whh, const u16* __restrict__ whl,
                           const float* __restrict__ xcat, const float* __restrict__ bhr,
                           const float* __restrict__ bhz, const float* __restrict__ bhg,
                           const float* __restrict__ hp, const u16* __restrict__ hph,
                           const u16* __restrict__ hpl, float* __restrict__ hn,
                           u16* __restrict__ hnh, u16* __restrict__ hnl,
                           u16* __restrict__ hiddf, int s) {
  __shared__ float red[3][4][16][16];
  int tid = threadIdx.x;
  int w = tid >> 6, l = tid & 63;
  int jtile = blockIdx.x & 63, mhalf = blockIdx.x >> 6;

  // epilogue operand prefetch (HBM latency hides under MFMA phase)
  int erow = tid >> 4, ecol = tid & 15;
  int eb = mhalf * 16 + erow, ej = jtile * 16 + ecol;
  float xr = 0.f, xz = 0.f, xg = 0.f, hprev = 0.f, br = 0.f, bz = 0.f, bg = 0.f;
  if (tid < 256) {
    const float* xrow = xcat + ((size_t)eb * S_ + s) * 3072;
    xr = xrow[ej]; xz = xrow[1024 + ej]; xg = xrow[2048 + ej];
    hprev = hp[(size_t)eb * H_ + ej];
    br = bhr[ej]; bz = bhz[ej]; bg = bhg[ej];
  }

  int gate = w >> 2, kg = w & 3;
  int lr = l & 15, lk = (l >> 4) << 3;
  int brow = mhalf * 16 + lr;
  const u16* hbase_h = hph + (size_t)brow * H_;
  const u16* hbase_l = hpl + (size_t)brow * H_;
  size_t wb = (size_t)(jtile * 3 + gate) * 32 * 512;
  f32x4 acc = {};
#pragma unroll
  for (int t = 0; t < 8; ++t) {
    int kt = kg * 8 + t;
    int k = kt * 32 + lk;
    short8 ah = *reinterpret_cast<const short8*>(hbase_h + k);
    short8 al = *reinterpret_cast<const short8*>(hbase_l + k);
    size_t u = wb + ((size_t)kt * 64 + l) * 8;
    short8 bh = *reinterpret_cast<const short8*>(whh + u);
    short8 bl = *reinterpret_cast<const short8*>(whl + u);
    acc = __builtin_amdgcn_mfma_f32_16x16x32_bf16(ah, bh, acc, 0, 0, 0);
    acc = __builtin_amdgcn_mfma_f32_16x16x32_bf16(ah, bl, acc, 0, 0, 0);
    acc = __builtin_amdgcn_mfma_f32_16x16x32_bf16(al, bh, acc, 0, 0, 0);
  }
#pragma unroll
  for (int q = 0; q < 4; ++q)
    red[gate][kg][(l >> 4) * 4 + q][lr] = acc[q];
  __syncthreads();

  if (tid < 256) {
    float ar = br + xr, az = bz + xz, ag = bg;
#pragma unroll
    for (int kg2 = 0; kg2 < 4; ++kg2) {
      ar += red[0][kg2][erow][ecol];
      az += red[1][kg2][erow][ecol];
      ag += red[2][kg2][erow][ecol];
    }
    float r = 1.f / (1.f + __expf(-ar));
    float z = 1.f / (1.f + __expf(-az));
    float ta = xg + r * ag;
    float gv = 1.f - 2.f / (__expf(2.f * ta) + 1.f);  // tanh
    float hnew = (1.f - z) * gv + z * hprev;
    hn[(size_t)eb * H_ + ej] = hnew;
    u16 hi = f2bf(hnew);
    hnh[(size_t)eb * H_ + ej] = hi;
    hnl[(size_t)eb * H_ + ej] = f2bf(hnew - bf2f(hi));
    // hidd in A-frag order for the output GEMM: row = b*S + s, k = ej
    int row = eb * S_ + s;
    int ktO = ej >> 5, mtO = row >> 4, laneO = (row & 15) + 16 * ((ej >> 3) & 3);
    hiddf[(((size_t)ktO * 256 + mtO) * 64 + laneO) * 8 + (ej & 7)] = hi;
  }
}

extern "C" void kernel_launch(void* const* d_in, const int* in_sizes, int n_in,
                              void* d_out, int out_size, void* d_ws, size_t ws_size,
                              hipStream_t stream) {
  const int*   inputs      = (const int*)d_in[0];
  const float* hidden_init = (const float*)d_in[2];
  const float* E    = (const float*)d_in[3];
  const float* Wxr  = (const float*)d_in[4];  const float* bxr = (const float*)d_in[5];
  const float* Wxz  = (const float*)d_in[6];  const float* bxz = (const float*)d_in[7];
  const float* Wxg  = (const float*)d_in[8];  const float* bxg = (const float*)d_in[9];
  const float* Whr  = (const float*)d_in[10]; const float* bhr = (const float*)d_in[11];
  const float* Whz  = (const float*)d_in[12]; const float* bhz = (const float*)d_in[13];
  const float* Whg  = (const float*)d_in[14]; const float* bhg = (const float*)d_in[15];
  const float* Wout = (const float*)d_in[16]; const float* bout = (const float*)d_in[17];
  float* out = (float*)d_out;

  char* ws = (char*)d_ws;
  u16* wxf    = (u16*)(ws);                    //  6,291,456
  u16* wof    = (u16*)(ws + 6291456);          // 65,536,000
  u16* embf   = (u16*)(ws + 71827456);         //  8,388,608 (aliased: hiddf after xproj)
  u16* hiddf  = embf;                          //  alias — emb fully consumed by xproj first
  float* bcat = (float*)(ws + 80216064);       //     12,288
  float* xcat = (float*)(ws + 80228352);       // 50,331,648
  u16* whh    = (u16*)(ws + 130560000);        //  6,291,456
  u16* whl    = (u16*)(ws + 136851456);        //  6,291,456
  float* hpb  = (float*)(ws + 143142912);      //    262,144 (2 slots)
  u16* hhb    = (u16*)(ws + 143405056);        //    131,072 (2 slots)
  u16* hlb    = (u16*)(ws + 143536128);        //    131,072 (2 slots)

  k_gather_embed<<<2048, 256, 0, stream>>>(inputs, E, embf);
  k_cvt_wx<<<1536, 256, 0, stream>>>(Wxr, Wxz, Wxg, wxf);
  k_cvt_wout<<<16000, 256, 0, stream>>>(Wout, wof);
  k_prep_wh<<<1536, 256, 0, stream>>>(Whr, Whz, Whg, whh, whl);
  k_prep_h0<<<128, 256, 0, stream>>>(hidden_init, hpb, hhb, hlb);
  k_bcat<<<12, 256, 0, stream>>>(bxr, bxz, bxg, bcat);

  // x-projections: [4096][3072] fp32
  k_gemm_frag<<<dim3(24, 32), 256, 0, stream>>>(embf, wxf, bcat, xcat, 256, 192, 32, 3072);

  // recurrence
  for (int s = 0; s < S_; ++s) {
    int pi = s & 1, po = pi ^ 1;
    k_gru_step<<<128, 768, 0, stream>>>(whh, whl, xcat, bhr, bhz, bhg,
                                        hpb + pi * (B_ * H_), hhb + pi * (B_ * H_), hlb + pi * (B_ * H_),
                                        hpb + po * (B_ * H_), hhb + po * (B_ * H_), hlb + po * (B_ * H_),
                                        hiddf, s);
  }

  // output: [4096][32000] fp32
  k_gemm_frag<<<dim3(250, 32), 256, 0, stream>>>(hiddf, wof, bout, out, 256, 2000, 32, 32000);
}